// Round 1
// baseline (5945.355 us; speedup 1.0000x reference)
//
#include <hip/hip_runtime.h>

namespace {

constexpr int T_STEPS = 2048;
constexpr int BATCH   = 512;
constexpr int IN      = 64;
constexpr int H       = 128;
constexpr int OUT     = 10;
constexpr int BDIM    = 256;   // 4 waves
constexpr int CHUNK   = 16;    // x-prefetch chunk (steps)
constexpr int NCHUNK  = T_STEPS / CHUNK;

__device__ __forceinline__ float fast_tanh(float x) {
    // tanh(x) = 1 - 2/(exp(2x)+1); exact at +-inf, ~1e-7 err, no NaN
    float e = __expf(2.0f * x);
    return 1.0f - 2.0f / (e + 1.0f);
}

__global__ __launch_bounds__(BDIM, 2) void rnn2_scan(
    const float* __restrict__ x,       // (512, 2048, 64)
    const float* __restrict__ hidden,  // (2, 512, 128)
    const float* __restrict__ Wi0,     // (128, 64)
    const float* __restrict__ bi0,     // (128)
    const float* __restrict__ Wh0,     // (128, 128)
    const float* __restrict__ bh0,     // (128)
    const float* __restrict__ Wi1,     // (128, 128)
    const float* __restrict__ bi1,     // (128)
    const float* __restrict__ Wh1,     // (128, 128)
    const float* __restrict__ bh1,     // (128)
    const float* __restrict__ Wfc,     // (10, 128)
    const float* __restrict__ bfc,     // (10)
    float* __restrict__ out)           // 5120 | 65536 | 65536
{
    const int b    = blockIdx.x;       // batch row
    const int tid  = threadIdx.x;
    const int d    = tid & (H - 1);    // output hidden dim owned
    const int half = tid >> 7;         // K-split half (wave-uniform)

    __shared__ __align__(16) float xs[2][CHUNK][IN];  // x double-buffer
    __shared__ __align__(16) float h0s[H];
    __shared__ __align__(16) float h1s[H];
    __shared__ __align__(16) float psA[BDIM];         // layer-0 partials
    __shared__ __align__(16) float psB[BDIM];         // layer-1 partials

    // ---- per-thread weight registers (K-split: this thread's half of K) ----
    float wi0[IN / 2];  // 32
    float wh0[H / 2];   // 64
    float wi1[H / 2];   // 64
    float wh1[H / 2];   // 64
    {
        const float* p = Wi0 + d * IN + half * (IN / 2);
        #pragma unroll
        for (int j = 0; j < IN / 2; j += 4) {
            float4 v = *(const float4*)(p + j);
            wi0[j] = v.x; wi0[j + 1] = v.y; wi0[j + 2] = v.z; wi0[j + 3] = v.w;
        }
    }
    {
        const float* p = Wh0 + d * H + half * (H / 2);
        #pragma unroll
        for (int j = 0; j < H / 2; j += 4) {
            float4 v = *(const float4*)(p + j);
            wh0[j] = v.x; wh0[j + 1] = v.y; wh0[j + 2] = v.z; wh0[j + 3] = v.w;
        }
    }
    {
        const float* p = Wi1 + d * H + half * (H / 2);
        #pragma unroll
        for (int j = 0; j < H / 2; j += 4) {
            float4 v = *(const float4*)(p + j);
            wi1[j] = v.x; wi1[j + 1] = v.y; wi1[j + 2] = v.z; wi1[j + 3] = v.w;
        }
    }
    {
        const float* p = Wh1 + d * H + half * (H / 2);
        #pragma unroll
        for (int j = 0; j < H / 2; j += 4) {
            float4 v = *(const float4*)(p + j);
            wh1[j] = v.x; wh1[j + 1] = v.y; wh1[j + 2] = v.z; wh1[j + 3] = v.w;
        }
    }

    float bias0 = 0.0f, bias1 = 0.0f;
    if (tid < H) {
        bias0 = bi0[tid] + bh0[tid];
        bias1 = bi1[tid] + bh1[tid];
        h0s[tid] = hidden[b * H + tid];                  // layer 0 init
        h1s[tid] = hidden[BATCH * H + b * H + tid];      // layer 1 init
    }

    // ---- x chunk prefetch: chunk0 -> LDS, chunk1 -> regs ----
    const float* xrow = x + (size_t)b * (T_STEPS * IN);
    float4 R;
    {
        *(float4*)(&xs[0][0][0] + tid * 4) = *(const float4*)(xrow + tid * 4);
        R = *(const float4*)(xrow + CHUNK * IN + tid * 4);
    }
    __syncthreads();

    for (int t = 0; t < T_STEPS; ++t) {
        const int c  = t >> 4;           // chunk index
        const int ph = t & (CHUNK - 1);  // step within chunk
        if (ph == 0 && c > 0) {
            // commit prefetched chunk c, then issue load of chunk c+1
            *(float4*)(&xs[c & 1][0][0] + tid * 4) = R;
            __syncthreads();
            if (c + 1 < NCHUNK)
                R = *(const float4*)(xrow + (size_t)(c + 1) * (CHUNK * IN) + tid * 4);
        }

        // ---- layer 0 partials: dot(Wi0[d], x_t) + dot(Wh0[d], h0) over this half of K
        const float* xc  = &xs[c & 1][ph][half * (IN / 2)];
        const float* h0p = &h0s[half * (H / 2)];
        float a0 = 0.f, a1 = 0.f, a2 = 0.f, a3 = 0.f;
        #pragma unroll
        for (int j = 0; j < IN / 2; j += 4) {
            float4 v = *(const float4*)(xc + j);
            a0 += wi0[j] * v.x; a1 += wi0[j + 1] * v.y;
            a2 += wi0[j + 2] * v.z; a3 += wi0[j + 3] * v.w;
        }
        #pragma unroll
        for (int j = 0; j < H / 2; j += 4) {
            float4 v = *(const float4*)(h0p + j);
            a0 += wh0[j] * v.x; a1 += wh0[j + 1] * v.y;
            a2 += wh0[j + 2] * v.z; a3 += wh0[j + 3] * v.w;
        }
        psA[tid] = (a0 + a1) + (a2 + a3);
        __syncthreads();                       // B1: psA ready
        if (tid < H) {
            h0s[tid] = fast_tanh(psA[tid] + psA[tid + H] + bias0);
        }
        __syncthreads();                       // B2: h0s (new) ready

        // ---- layer 1 partials: dot(Wi1[d], h0_new) + dot(Wh1[d], h1)
        const float* h0q = &h0s[half * (H / 2)];
        const float* h1p = &h1s[half * (H / 2)];
        float c0 = 0.f, c1 = 0.f, c2 = 0.f, c3 = 0.f;
        #pragma unroll
        for (int j = 0; j < H / 2; j += 4) {
            float4 v = *(const float4*)(h0q + j);
            c0 += wi1[j] * v.x; c1 += wi1[j + 1] * v.y;
            c2 += wi1[j + 2] * v.z; c3 += wi1[j + 3] * v.w;
        }
        #pragma unroll
        for (int j = 0; j < H / 2; j += 4) {
            float4 v = *(const float4*)(h1p + j);
            c0 += wh1[j] * v.x; c1 += wh1[j + 1] * v.y;
            c2 += wh1[j + 2] * v.z; c3 += wh1[j + 3] * v.w;
        }
        psB[tid] = (c0 + c1) + (c2 + c3);
        __syncthreads();                       // B3: psB ready
        if (tid < H) {
            h1s[tid] = fast_tanh(psB[tid] + psB[tid + H] + bias1);
        }
        // no 4th barrier: h1s next read (layer-1 stage of t+1) is after B2 of t+1,
        // psB next write is after B2 of t+1; psA/h0s races separated by B1/B2.
    }
    __syncthreads();   // h0s/h1s final values visible to epilogue readers

    // ---- epilogue: fc head + final hidden states ----
    if (tid < OUT) {
        float acc = bfc[tid];
        const float* w = Wfc + tid * H;
        #pragma unroll 8
        for (int k = 0; k < H; ++k) acc += w[k] * h1s[k];
        out[b * OUT + tid] = acc;
    }
    if (tid < H) {
        out[BATCH * OUT + b * H + tid]             = h0s[tid];  // hidden_out[0]
        out[BATCH * OUT + BATCH * H + b * H + tid] = h1s[tid];  // hidden_out[1]
    }
}

} // namespace

extern "C" void kernel_launch(void* const* d_in, const int* in_sizes, int n_in,
                              void* d_out, int out_size, void* d_ws, size_t ws_size,
                              hipStream_t stream) {
    const float* x   = (const float*)d_in[0];
    const float* hid = (const float*)d_in[1];
    const float* Wi0 = (const float*)d_in[2];
    const float* bi0 = (const float*)d_in[3];
    const float* Wh0 = (const float*)d_in[4];
    const float* bh0 = (const float*)d_in[5];
    const float* Wi1 = (const float*)d_in[6];
    const float* bi1 = (const float*)d_in[7];
    const float* Wh1 = (const float*)d_in[8];
    const float* bh1 = (const float*)d_in[9];
    const float* Wfc = (const float*)d_in[10];
    const float* bfc = (const float*)d_in[11];
    float* out = (float*)d_out;

    hipLaunchKernelGGL(rnn2_scan, dim3(BATCH), dim3(BDIM), 0, stream,
                       x, hid, Wi0, bi0, Wh0, bh0, Wi1, bi1, Wh1, bh1, Wfc, bfc, out);
}

// Round 2
// 2374.783 us; speedup vs baseline: 2.5035x; 2.5035x over previous
//
#include <hip/hip_runtime.h>
#include <stdint.h>

namespace {

constexpr int T_STEPS = 2048;
constexpr int BATCH   = 512;
constexpr int IN      = 64;
constexpr int H       = 128;
constexpr int OUT     = 10;
constexpr int BDIM    = 256;   // 4 waves
constexpr int CHUNK   = 16;    // x/xp prefetch chunk (steps)
constexpr int NCHUNK  = T_STEPS / CHUNK;

typedef _Float16 half2v __attribute__((ext_vector_type(2)));

__device__ __forceinline__ float dot2(uint32_t a, uint32_t b, float c) {
#if __has_builtin(__builtin_amdgcn_fdot2)
    return __builtin_amdgcn_fdot2(__builtin_bit_cast(half2v, a),
                                  __builtin_bit_cast(half2v, b), c, false);
#else
    half2v av = __builtin_bit_cast(half2v, a);
    half2v bv = __builtin_bit_cast(half2v, b);
    return c + (float)av[0] * (float)bv[0] + (float)av[1] * (float)bv[1];
#endif
}

__device__ __forceinline__ uint32_t packh2(float lo, float hi) {
    half2v v; v[0] = (_Float16)lo; v[1] = (_Float16)hi;
    return __builtin_bit_cast(uint32_t, v);
}

__device__ __forceinline__ float fast_tanh(float x) {
    // tanh(x) = 1 - 2/(exp(2x)+1); exact at +-inf, ~1e-7 err, no NaN
    float e = __expf(2.0f * x);
    return 1.0f - 2.0f / (e + 1.0f);
}

// ============ kernel 1: xp[b,t,h] = f16( x[b,t,:]@Wi0[h,:] + bi0[h] + bh0[h] )
__global__ __launch_bounds__(256) void xproj_kernel(
    const float* __restrict__ x, const float* __restrict__ Wi0,
    const float* __restrict__ bi0, const float* __restrict__ bh0,
    _Float16* __restrict__ xp)
{
    constexpr int TOK = 64;
    __shared__ __align__(16) float xs[TOK][IN];   // 16 KB
    __shared__ __align__(16) float ws[H][IN];     // 32 KB
    __shared__ float bsum[H];

    const int tid = threadIdx.x;
    const size_t tok0 = (size_t)blockIdx.x * TOK;

    {   // stage x tile (4096 f32, coalesced)
        const float4* src = (const float4*)(x + tok0 * IN);
        float4* dst = (float4*)&xs[0][0];
        #pragma unroll
        for (int r = 0; r < 4; ++r) dst[tid + r * 256] = src[tid + r * 256];
    }
    {   // stage Wi0 (8192 f32)
        const float4* src = (const float4*)Wi0;
        float4* dst = (float4*)&ws[0][0];
        #pragma unroll
        for (int r = 0; r < 8; ++r) dst[tid + r * 256] = src[tid + r * 256];
    }
    if (tid < H) bsum[tid] = bi0[tid] + bh0[tid];
    __syncthreads();

    const int tk = tid & (TOK - 1);
    const int dg = (tid >> 6) * 32;     // dim group (wave-uniform)

    float xr[IN];
    #pragma unroll
    for (int k = 0; k < IN; k += 4) {
        float4 v = *(const float4*)&xs[tk][k];
        xr[k] = v.x; xr[k+1] = v.y; xr[k+2] = v.z; xr[k+3] = v.w;
    }

    uint32_t ob[16];
    #pragma unroll
    for (int dd = 0; dd < 32; dd += 2) {
        const int d0 = dg + dd;
        float a = bsum[d0], bacc = bsum[d0 + 1];
        #pragma unroll
        for (int k = 0; k < IN; k += 4) {
            float4 w0 = *(const float4*)&ws[d0][k];      // wave-uniform (broadcast)
            float4 w1 = *(const float4*)&ws[d0 + 1][k];
            a = fmaf(w0.x, xr[k], a);   a = fmaf(w0.y, xr[k+1], a);
            a = fmaf(w0.z, xr[k+2], a); a = fmaf(w0.w, xr[k+3], a);
            bacc = fmaf(w1.x, xr[k], bacc);   bacc = fmaf(w1.y, xr[k+1], bacc);
            bacc = fmaf(w1.z, xr[k+2], bacc); bacc = fmaf(w1.w, xr[k+3], bacc);
        }
        ob[dd >> 1] = packh2(a, bacc);
    }
    uint4* dst = (uint4*)(xp + (tok0 + tk) * H + dg);
    #pragma unroll
    for (int r = 0; r < 4; ++r) dst[r] = ((const uint4*)ob)[r];
}

// ============ kernel 2: the fused 2-layer scan, 1 batch row / block
template<bool XP>
__global__ __launch_bounds__(BDIM, 2) void rnn2_scan(
    const float* __restrict__ x,
    const _Float16* __restrict__ xp,
    const float* __restrict__ hidden,
    const float* __restrict__ Wi0, const float* __restrict__ bi0,
    const float* __restrict__ Wh0, const float* __restrict__ bh0,
    const float* __restrict__ Wi1, const float* __restrict__ bi1,
    const float* __restrict__ Wh1, const float* __restrict__ bh1,
    const float* __restrict__ Wfc, const float* __restrict__ bfc,
    float* __restrict__ out)
{
    const int b    = blockIdx.x;
    const int tid  = threadIdx.x;
    const int W    = tid >> 6;           // wave id: owns dims [W*32, W*32+32)
    const int l    = tid & 63;
    const int dim  = W * 32 + (l & 31);
    const int half = l >> 5;             // K-half within wave

    __shared__ __align__(16) uint32_t h0h[2][H / 2];   // packed f16 pairs, dbuf
    __shared__ __align__(16) uint32_t h1h[2][H / 2];
    __shared__ __align__(16) _Float16 xps[2][CHUNK][H];  // XP path (8 KB)
    __shared__ __align__(16) float    xsf[2][CHUNK][IN]; // fallback (8 KB)
    __shared__ float h0f[H], h1f[H];                   // f32 finals for epilogue

    // ---- weights: packed f16 pairs, this thread's K-half of its dim's rows
    uint32_t wh0[32], wi1[32], wh1[32];
    {
        const float* p = Wh0 + dim * H + half * 64;
        #pragma unroll
        for (int j = 0; j < 32; ++j) { float2 f = *(const float2*)(p + 2*j); wh0[j] = packh2(f.x, f.y); }
        p = Wi1 + dim * H + half * 64;
        #pragma unroll
        for (int j = 0; j < 32; ++j) { float2 f = *(const float2*)(p + 2*j); wi1[j] = packh2(f.x, f.y); }
        p = Wh1 + dim * H + half * 64;
        #pragma unroll
        for (int j = 0; j < 32; ++j) { float2 f = *(const float2*)(p + 2*j); wh1[j] = packh2(f.x, f.y); }
    }
    float wi0f[32];
    float bias0 = 0.0f;
    if constexpr (!XP) {
        const float* p = Wi0 + dim * IN + half * 32;
        #pragma unroll
        for (int j = 0; j < 32; ++j) wi0f[j] = p[j];
        bias0 = bi0[dim] + bh0[dim];
    }
    const float bias1 = bi1[dim] + bh1[dim];

    // ---- init hidden into buffer 1 (prv of t=0)
    if (tid < 64) {
        h0h[1][tid] = packh2(hidden[b * H + 2 * tid], hidden[b * H + 2 * tid + 1]);
    } else if (tid < 128) {
        const int q = tid - 64;
        h1h[1][q] = packh2(hidden[BATCH * H + b * H + 2 * q],
                           hidden[BATCH * H + b * H + 2 * q + 1]);
    }

    // ---- prefetch: chunk0 -> LDS, chunk1 -> regs (4 KB chunks either path)
    uint4 R;
    if constexpr (XP) {
        const uint4* src = (const uint4*)(xp + (size_t)b * T_STEPS * H);
        ((uint4*)&xps[0][0][0])[tid] = src[tid];
        R = src[256 + tid];
    } else {
        const uint4* src = (const uint4*)(x + (size_t)b * T_STEPS * IN);
        ((uint4*)&xsf[0][0][0])[tid] = src[tid];
        R = src[256 + tid];
    }
    __syncthreads();

    for (int t = 0; t < T_STEPS; ++t) {
        const int c   = t >> 4;
        const int ph  = t & (CHUNK - 1);
        const int cur = t & 1;
        const int prv = cur ^ 1;

        // ======== layer 0: dot(Wh0[dim], h0_prev) over this K-half
        float a0 = 0.f, a1 = 0.f, a2 = 0.f, a3 = 0.f;
        {
            const uint4* hp = (const uint4*)&h0h[prv][half * 32];  // broadcast reads
            #pragma unroll
            for (int r = 0; r < 8; ++r) {
                uint4 hv = hp[r];
                a0 = dot2(wh0[4*r+0], hv.x, a0);
                a1 = dot2(wh0[4*r+1], hv.y, a1);
                a2 = dot2(wh0[4*r+2], hv.z, a2);
                a3 = dot2(wh0[4*r+3], hv.w, a3);
            }
        }
        float acc = (a0 + a1) + (a2 + a3);
        float xadd;
        if constexpr (XP) {
            xadd = (float)xps[c & 1][ph][dim];     // bias0 already folded in
        } else {
            float s0 = 0.f, s1 = 0.f, s2 = 0.f, s3 = 0.f;
            const float4* xq = (const float4*)&xsf[c & 1][ph][half * 32];
            #pragma unroll
            for (int r = 0; r < 8; ++r) {
                float4 v = xq[r];
                s0 = fmaf(wi0f[4*r+0], v.x, s0);
                s1 = fmaf(wi0f[4*r+1], v.y, s1);
                s2 = fmaf(wi0f[4*r+2], v.z, s2);
                s3 = fmaf(wi0f[4*r+3], v.w, s3);
            }
            acc += (s0 + s1) + (s2 + s3);          // per-half partial, pre-shfl
            xadd = bias0;
        }
        acc += __shfl_xor(acc, 32);                // combine K-halves
        const float v0  = fast_tanh(acc + xadd);
        const float v0p = __shfl_xor(v0, 1);       // pair partner's value
        if ((l & 33) == 0)                         // even lane of low half writes pair
            h0h[cur][W * 16 + (l >> 1)] = packh2(v0, v0p);
        if (t == T_STEPS - 1 && l < 32) h0f[dim] = v0;

        __syncthreads();   // the ONE barrier per step: h0h[cur] visible

        // ======== layer 1: dot(Wi1[dim], h0_new) + dot(Wh1[dim], h1_prev)
        float c0 = 0.f, c1 = 0.f, c2 = 0.f, c3 = 0.f;
        {
            const uint4* hp = (const uint4*)&h0h[cur][half * 32];
            #pragma unroll
            for (int r = 0; r < 8; ++r) {
                uint4 hv = hp[r];
                c0 = dot2(wi1[4*r+0], hv.x, c0);
                c1 = dot2(wi1[4*r+1], hv.y, c1);
                c2 = dot2(wi1[4*r+2], hv.z, c2);
                c3 = dot2(wi1[4*r+3], hv.w, c3);
            }
            const uint4* gp = (const uint4*)&h1h[prv][half * 32];
            #pragma unroll
            for (int r = 0; r < 8; ++r) {
                uint4 gv = gp[r];
                c0 = dot2(wh1[4*r+0], gv.x, c0);
                c1 = dot2(wh1[4*r+1], gv.y, c1);
                c2 = dot2(wh1[4*r+2], gv.z, c2);
                c3 = dot2(wh1[4*r+3], gv.w, c3);
            }
        }
        float acc1 = (c0 + c1) + (c2 + c3);
        acc1 += __shfl_xor(acc1, 32);
        const float v1  = fast_tanh(acc1 + bias1);
        const float v1p = __shfl_xor(v1, 1);
        if ((l & 33) == 0)
            h1h[cur][W * 16 + (l >> 1)] = packh2(v1, v1p);
        if (t == T_STEPS - 1 && l < 32) h1f[dim] = v1;

        // ---- mid-chunk: commit prefetched chunk c+1, issue load of c+2.
        // Safe: we're past B1(t), so every wave finished reading chunk c-1
        // (its last read was L0 of step 16c-1); buf (c+1)&1 is dead. Current
        // readers use buf c&1. Visibility to first read (t=16c+16) via the
        // intervening per-step barriers.
        if (ph == 8) {
            if constexpr (XP) {
                if (c + 1 < NCHUNK) ((uint4*)&xps[(c + 1) & 1][0][0])[tid] = R;
                if (c + 2 < NCHUNK)
                    R = ((const uint4*)(xp + (size_t)b * T_STEPS * H))[(size_t)(c + 2) * 256 + tid];
            } else {
                if (c + 1 < NCHUNK) ((uint4*)&xsf[(c + 1) & 1][0][0])[tid] = R;
                if (c + 2 < NCHUNK)
                    R = ((const uint4*)(x + (size_t)b * T_STEPS * IN))[(size_t)(c + 2) * 256 + tid];
            }
        }
    }
    __syncthreads();   // h0f/h1f + last h writes visible

    // ---- epilogue
    if (tid < OUT) {
        float acc = bfc[tid];
        const float* w = Wfc + tid * H;
        #pragma unroll 8
        for (int k = 0; k < H; ++k) acc = fmaf(w[k], h1f[k], acc);
        out[(size_t)b * OUT + tid] = acc;
    }
    if (tid < H) {
        out[BATCH * OUT + (size_t)b * H + tid]             = h0f[tid];
        out[BATCH * OUT + BATCH * H + (size_t)b * H + tid] = h1f[tid];
    }
}

} // namespace

extern "C" void kernel_launch(void* const* d_in, const int* in_sizes, int n_in,
                              void* d_out, int out_size, void* d_ws, size_t ws_size,
                              hipStream_t stream) {
    const float* x   = (const float*)d_in[0];
    const float* hid = (const float*)d_in[1];
    const float* Wi0 = (const float*)d_in[2];
    const float* bi0 = (const float*)d_in[3];
    const float* Wh0 = (const float*)d_in[4];
    const float* bh0 = (const float*)d_in[5];
    const float* Wi1 = (const float*)d_in[6];
    const float* bi1 = (const float*)d_in[7];
    const float* Wh1 = (const float*)d_in[8];
    const float* bh1 = (const float*)d_in[9];
    const float* Wfc = (const float*)d_in[10];
    const float* bfc = (const float*)d_in[11];
    float* out = (float*)d_out;

    const size_t xp_bytes = (size_t)BATCH * T_STEPS * H * sizeof(_Float16);
    if (ws_size >= xp_bytes) {
        _Float16* xpw = (_Float16*)d_ws;
        hipLaunchKernelGGL(xproj_kernel, dim3((BATCH * T_STEPS) / 64), dim3(256), 0, stream,
                           x, Wi0, bi0, bh0, xpw);
        hipLaunchKernelGGL((rnn2_scan<true>), dim3(BATCH), dim3(BDIM), 0, stream,
                           x, (const _Float16*)xpw, hid, Wi0, bi0, Wh0, bh0,
                           Wi1, bi1, Wh1, bh1, Wfc, bfc, out);
    } else {
        hipLaunchKernelGGL((rnn2_scan<false>), dim3(BATCH), dim3(BDIM), 0, stream,
                           x, (const _Float16*)nullptr, hid, Wi0, bi0, Wh0, bh0,
                           Wi1, bi1, Wh1, bh1, Wfc, bfc, out);
    }
}

// Round 3
// 1707.007 us; speedup vs baseline: 3.4829x; 1.3912x over previous
//
#include <hip/hip_runtime.h>
#include <stdint.h>

namespace {

constexpr int T_STEPS = 2048;
constexpr int BATCH   = 512;
constexpr int IN      = 64;
constexpr int H       = 128;
constexpr int OUT     = 10;
constexpr int BDIM    = 256;   // 4 waves
constexpr int CHUNK   = 16;    // x prefetch chunk (steps)
constexpr int NCHUNK  = T_STEPS / CHUNK;   // 128

typedef _Float16 half2v __attribute__((ext_vector_type(2)));

__device__ __forceinline__ float dot2(uint32_t a, uint32_t b, float c) {
#if __has_builtin(__builtin_amdgcn_fdot2)
    return __builtin_amdgcn_fdot2(__builtin_bit_cast(half2v, a),
                                  __builtin_bit_cast(half2v, b), c, false);
#else
    half2v av = __builtin_bit_cast(half2v, a);
    half2v bv = __builtin_bit_cast(half2v, b);
    return c + (float)av[0] * (float)bv[0] + (float)av[1] * (float)bv[1];
#endif
}

__device__ __forceinline__ uint32_t packh2(float lo, float hi) {
    half2v v; v[0] = (_Float16)lo; v[1] = (_Float16)hi;
    return __builtin_bit_cast(uint32_t, v);
}

__device__ __forceinline__ float fast_tanh(float x) {
    float e = __expf(2.0f * x);
    return 1.0f - 2.0f / (e + 1.0f);
}

// Fused 2-layer scan, 1 batch row / block, software-pipelined:
// each barrier interval computes L1(t) AND L0(t+1) (independent work).
__global__ __launch_bounds__(BDIM, 2) void rnn2_scan(
    const float* __restrict__ x,
    const float* __restrict__ hidden,
    const float* __restrict__ Wi0, const float* __restrict__ bi0,
    const float* __restrict__ Wh0, const float* __restrict__ bh0,
    const float* __restrict__ Wi1, const float* __restrict__ bi1,
    const float* __restrict__ Wh1, const float* __restrict__ bh1,
    const float* __restrict__ Wfc, const float* __restrict__ bfc,
    float* __restrict__ out)
{
    const int b    = blockIdx.x;
    const int tid  = threadIdx.x;
    const int W    = tid >> 6;           // wave id: owns dims [W*32, W*32+32)
    const int l    = tid & 63;
    const int dim  = W * 32 + (l & 31);
    const int half = l >> 5;             // K-half within wave

    // h(t) parity convention: h?h[t & 1] holds h?(t); inits live in parity 1.
    __shared__ __align__(16) uint32_t h0h[2][H / 2];     // packed f16 pairs
    __shared__ __align__(16) uint32_t h1h[2][H / 2];
    __shared__ __align__(16) uint32_t xs[2][CHUNK][IN / 2];  // x as f16 pairs, 4 KB
    __shared__ float h0f[H], h1f[H];

    // ---- weights: packed f16 pairs, this thread's K-half of its dim's rows
    uint32_t wh0[32], wi1[32], wh1[32], wi0h[16];
    {
        const float* p = Wh0 + dim * H + half * 64;
        #pragma unroll
        for (int j = 0; j < 32; ++j) { float2 f = *(const float2*)(p + 2*j); wh0[j] = packh2(f.x, f.y); }
        p = Wi1 + dim * H + half * 64;
        #pragma unroll
        for (int j = 0; j < 32; ++j) { float2 f = *(const float2*)(p + 2*j); wi1[j] = packh2(f.x, f.y); }
        p = Wh1 + dim * H + half * 64;
        #pragma unroll
        for (int j = 0; j < 32; ++j) { float2 f = *(const float2*)(p + 2*j); wh1[j] = packh2(f.x, f.y); }
        p = Wi0 + dim * IN + half * 32;
        #pragma unroll
        for (int j = 0; j < 16; ++j) { float2 f = *(const float2*)(p + 2*j); wi0h[j] = packh2(f.x, f.y); }
    }
    const float bias0 = bi0[dim] + bh0[dim];
    const float bias1 = bi1[dim] + bh1[dim];

    // ---- init hidden into parity-1 buffers
    if (tid < 64) {
        h0h[1][tid] = packh2(hidden[b * H + 2 * tid], hidden[b * H + 2 * tid + 1]);
    } else if (tid < 128) {
        const int q = tid - 64;
        h1h[1][q] = packh2(hidden[BATCH * H + b * H + 2 * q],
                           hidden[BATCH * H + b * H + 2 * q + 1]);
    }

    // ---- x prefetch: chunk0 packed into LDS, chunk1 raw in regs
    const float4* xrow = (const float4*)(x + (size_t)b * T_STEPS * IN);
    float4 R;
    {
        float4 v = xrow[tid];      // chunk0: 256 float4
        uint2 pk; pk.x = packh2(v.x, v.y); pk.y = packh2(v.z, v.w);
        ((uint2*)&xs[0][0][0])[tid] = pk;
        R = xrow[256 + tid];       // chunk1
    }
    __syncthreads();

    // ================= peel: L0(0) -> h0(0) into h0h[0]
    {
        float a0 = 0.f, a1 = 0.f, a2 = 0.f, a3 = 0.f;
        const uint4* hp = (const uint4*)&h0h[1][half * 32];
        const uint4* xq = (const uint4*)&xs[0][0][half * 16];
        #pragma unroll
        for (int r = 0; r < 8; ++r) {
            uint4 hv = hp[r];
            a0 = dot2(wh0[4*r+0], hv.x, a0);
            a1 = dot2(wh0[4*r+1], hv.y, a1);
            a2 = dot2(wh0[4*r+2], hv.z, a2);
            a3 = dot2(wh0[4*r+3], hv.w, a3);
        }
        #pragma unroll
        for (int r = 0; r < 4; ++r) {
            uint4 xv = xq[r];
            a0 = dot2(wi0h[4*r+0], xv.x, a0);
            a1 = dot2(wi0h[4*r+1], xv.y, a1);
            a2 = dot2(wi0h[4*r+2], xv.z, a2);
            a3 = dot2(wi0h[4*r+3], xv.w, a3);
        }
        float acc = (a0 + a1) + (a2 + a3);
        acc += __shfl_xor(acc, 32);
        const float v0  = fast_tanh(acc + bias0);
        const float v0p = __shfl_xor(v0, 1);
        if ((l & 33) == 0) h0h[0][W * 16 + (l >> 1)] = packh2(v0, v0p);
    }
    __syncthreads();

    // ================= main loop: interval t computes L1(t) || L0(t+1)
    for (int t = 0; t < T_STEPS - 1; ++t) {
        const int s  = t + 1;            // x step consumed by L0
        const int c  = s >> 4;
        const int ph = s & (CHUNK - 1);
        const int rp = t & 1;            // h0(t), and h1(t-1) in rp^1

        const uint4* hp = (const uint4*)&h0h[rp][half * 32];      // h0(t): shared by L1 & L0
        const uint4* gp = (const uint4*)&h1h[rp ^ 1][half * 32];  // h1(t-1)
        const uint4* xq = (const uint4*)&xs[c & 1][ph][half * 16];

        float a0 = 0.f, a1 = 0.f, a2 = 0.f, a3 = 0.f;   // L0(t+1)
        float c0 = 0.f, c1 = 0.f, c2 = 0.f, c3 = 0.f;   // L1(t)
        #pragma unroll
        for (int r = 0; r < 8; ++r) {
            uint4 hv = hp[r];
            uint4 gv = gp[r];
            a0 = dot2(wh0[4*r+0], hv.x, a0);
            a1 = dot2(wh0[4*r+1], hv.y, a1);
            a2 = dot2(wh0[4*r+2], hv.z, a2);
            a3 = dot2(wh0[4*r+3], hv.w, a3);
            c0 = dot2(wi1[4*r+0], hv.x, c0);
            c1 = dot2(wi1[4*r+1], hv.y, c1);
            c2 = dot2(wi1[4*r+2], hv.z, c2);
            c3 = dot2(wi1[4*r+3], hv.w, c3);
            c0 = dot2(wh1[4*r+0], gv.x, c0);
            c1 = dot2(wh1[4*r+1], gv.y, c1);
            c2 = dot2(wh1[4*r+2], gv.z, c2);
            c3 = dot2(wh1[4*r+3], gv.w, c3);
        }
        #pragma unroll
        for (int r = 0; r < 4; ++r) {
            uint4 xv = xq[r];
            a0 = dot2(wi0h[4*r+0], xv.x, a0);
            a1 = dot2(wi0h[4*r+1], xv.y, a1);
            a2 = dot2(wi0h[4*r+2], xv.z, a2);
            a3 = dot2(wi0h[4*r+3], xv.w, a3);
        }

        float acc0 = (a0 + a1) + (a2 + a3);
        float acc1 = (c0 + c1) + (c2 + c3);
        acc0 += __shfl_xor(acc0, 32);
        acc1 += __shfl_xor(acc1, 32);
        const float v0  = fast_tanh(acc0 + bias0);   // h0(t+1)
        const float v1  = fast_tanh(acc1 + bias1);   // h1(t)
        const float v0p = __shfl_xor(v0, 1);
        const float v1p = __shfl_xor(v1, 1);
        if ((l & 33) == 0) {
            const int w = W * 16 + (l >> 1);
            h0h[s & 1][w] = packh2(v0, v0p);
            h1h[t & 1][w] = packh2(v1, v1p);
        }
        if (s == T_STEPS - 1 && l < 32) h0f[dim] = v0;

        // ---- mid-chunk commit of chunk c+1 (already in R), prefetch c+2.
        // Buffer (c+1)&1 last read at s=16c-1 (interval 16c-2) — barriers since.
        if (ph == 8) {
            if (c + 1 < NCHUNK) {
                uint2 pk; pk.x = packh2(R.x, R.y); pk.y = packh2(R.z, R.w);
                ((uint2*)&xs[(c + 1) & 1][0][0])[tid] = pk;
            }
            if (c + 2 < NCHUNK) R = xrow[(size_t)(c + 2) * 256 + tid];
        }
        __syncthreads();
    }

    // ================= peel: L1(T-1)
    {
        const int t  = T_STEPS - 1;      // 2047
        const int rp = t & 1;            // 1
        float c0 = 0.f, c1 = 0.f, c2 = 0.f, c3 = 0.f;
        const uint4* hp = (const uint4*)&h0h[rp][half * 32];      // h0(2047)
        const uint4* gp = (const uint4*)&h1h[rp ^ 1][half * 32];  // h1(2046)
        #pragma unroll
        for (int r = 0; r < 8; ++r) {
            uint4 hv = hp[r];
            uint4 gv = gp[r];
            c0 = dot2(wi1[4*r+0], hv.x, c0);
            c1 = dot2(wi1[4*r+1], hv.y, c1);
            c2 = dot2(wi1[4*r+2], hv.z, c2);
            c3 = dot2(wi1[4*r+3], hv.w, c3);
            c0 = dot2(wh1[4*r+0], gv.x, c0);
            c1 = dot2(wh1[4*r+1], gv.y, c1);
            c2 = dot2(wh1[4*r+2], gv.z, c2);
            c3 = dot2(wh1[4*r+3], gv.w, c3);
        }
        float acc1 = (c0 + c1) + (c2 + c3);
        acc1 += __shfl_xor(acc1, 32);
        const float v1 = fast_tanh(acc1 + bias1);    // h1(2047)
        if (l < 32) h1f[dim] = v1;
    }
    __syncthreads();

    // ================= epilogue
    if (tid < OUT) {
        float acc = bfc[tid];
        const float* w = Wfc + tid * H;
        #pragma unroll 8
        for (int k = 0; k < H; ++k) acc = fmaf(w[k], h1f[k], acc);
        out[(size_t)b * OUT + tid] = acc;
    }
    if (tid < H) {
        out[BATCH * OUT + (size_t)b * H + tid]             = h0f[tid];
        out[BATCH * OUT + BATCH * H + (size_t)b * H + tid] = h1f[tid];
    }
}

} // namespace

extern "C" void kernel_launch(void* const* d_in, const int* in_sizes, int n_in,
                              void* d_out, int out_size, void* d_ws, size_t ws_size,
                              hipStream_t stream) {
    const float* x   = (const float*)d_in[0];
    const float* hid = (const float*)d_in[1];
    const float* Wi0 = (const float*)d_in[2];
    const float* bi0 = (const float*)d_in[3];
    const float* Wh0 = (const float*)d_in[4];
    const float* bh0 = (const float*)d_in[5];
    const float* Wi1 = (const float*)d_in[6];
    const float* bi1 = (const float*)d_in[7];
    const float* Wh1 = (const float*)d_in[8];
    const float* bh1 = (const float*)d_in[9];
    const float* Wfc = (const float*)d_in[10];
    const float* bfc = (const float*)d_in[11];
    float* out = (float*)d_out;

    hipLaunchKernelGGL(rnn2_scan, dim3(BATCH), dim3(BDIM), 0, stream,
                       x, hid, Wi0, bi0, Wh0, bh0, Wi1, bi1, Wh1, bh1, Wfc, bfc, out);
}